// Round 8
// baseline (94.427 us; speedup 1.0000x reference)
//
#include <hip/hip_runtime.h>

#define M 32                        // reflection coeffs
#define NC 33                       // floats per row
#define TPB 64                      // ONE wave per block
#define ROWS 128                    // rows per tile (2 per thread: t and t+64)
#define FPB (ROWS * NC)             // 4224 floats = 16896 B
#define V4R 16                      // float4 staging rounds: 16*64*4 = 4096 floats
#define TAILF 4096                  // last 128 floats: staged scalar (2 rounds)

typedef float f4 __attribute__((ext_vector_type(4)));
typedef float f2 __attribute__((ext_vector_type(2)));

__global__ __launch_bounds__(TPB, 2)
void lpc_to_parcor_kernel(const float* __restrict__ a,
                          float* __restrict__ out,
                          long long nrows) {
    __shared__ float lds[FPB];
    const int t = threadIdx.x;
    const long long base = (long long)blockIdx.x * FPB;   // tile start (floats)
    const long long limit = nrows * NC;
    const bool full = (base + FPB) <= limit;

    // ---- stage tile -> LDS (coalesced; contiguous b128 = conflict-free) ----
    if (full) {
        const f4* g4 = (const f4*)(a + base);
        f4* l4 = (f4*)lds;
#pragma unroll
        for (int k = 0; k < V4R; ++k)
            l4[t + k * TPB] = g4[t + k * TPB];
        lds[TAILF + t]       = a[base + TAILF + t];        // stride-1: conflict-free
        lds[TAILF + TPB + t] = a[base + TAILF + TPB + t];
    } else {
        for (int k = 0; k < 66; ++k) {           // 66*64 == FPB exactly
            int g = t + k * TPB;
            long long ga = base + g;
            lds[g] = (ga < limit) ? a[ga] : 0.0f;
        }
    }
    __syncthreads();

    // ---- packed Levinson: thread t owns rows t (.x) and t+64 (.y) ----
    // Row bases 33t and 33t+2112: (33t)%32 == (t)%32 and 2112%32 == 0, so every
    // LDS b32 access spreads over all 32 banks (2 lanes/bank = free).
    // Per-component math identical to the verified scalar recipe (R2 lesson:
    // exact IEEE div only).
    const int rb0 = t * NC;                      // row t
    const int rb1 = t * NC + 64 * NC;            // row t+64
    f2 ar[M];
#pragma unroll
    for (int j = 0; j < M; ++j) {
        ar[j].x = lds[rb0 + 1 + j];
        ar[j].y = lds[rb1 + 1 + j];
    }
#pragma unroll
    for (int m = M - 1; m >= 1; --m) {
        f2 km = ar[m];
        lds[rb0 + m + 1] = km.x;                 // out[..., m+1] row t
        lds[rb1 + m + 1] = km.y;                 // out[..., m+1] row t+64
        f2 z = 1.0f - km * km;
        f2 r;
        r.x = 1.0f / z.x;                        // exact IEEE div, 2 indep chains
        r.y = 1.0f / z.y;
        const int h = m >> 1;
#pragma unroll
        for (int j = 0; j < h; ++j) {            // packed symmetric pair update
            f2 x = ar[j], y = ar[m - 1 - j];
            ar[j]         = (x - km * y) * r;
            ar[m - 1 - j] = (y - km * x) * r;
        }
        if (m & 1) ar[h] = (ar[h] - km * ar[h]) * r;
    }
    lds[rb0 + 1] = ar[0].x;
    lds[rb1 + 1] = ar[0].y;
    // lds[rb0 + 0] / lds[rb1 + 0] still hold K for both rows.
    __syncthreads();

    // ---- store (coalesced, nontemporal) ----
    if (full) {
        const f4* l4 = (const f4*)lds;
#pragma unroll
        for (int k = 0; k < V4R; ++k) {
            f4 v = l4[t + k * TPB];
            __builtin_nontemporal_store(v, (f4*)(out + base) + t + k * TPB);
        }
        __builtin_nontemporal_store(lds[TAILF + t],       out + base + TAILF + t);
        __builtin_nontemporal_store(lds[TAILF + TPB + t], out + base + TAILF + TPB + t);
    } else {
        for (int k = 0; k < 66; ++k) {
            int g = t + k * TPB;
            long long ga = base + g;
            if (ga < limit) out[ga] = lds[g];
        }
    }
}

extern "C" void kernel_launch(void* const* d_in, const int* in_sizes, int n_in,
                              void* d_out, int out_size, void* d_ws, size_t ws_size,
                              hipStream_t stream) {
    const float* a = (const float*)d_in[0];
    float* out = (float*)d_out;
    long long nrows = (long long)in_sizes[0] / NC;
    long long ntiles = (nrows + ROWS - 1) / ROWS;
    lpc_to_parcor_kernel<<<(int)ntiles, TPB, 0, stream>>>(a, out, nrows);
}